// Round 11
// baseline (138.420 us; speedup 1.0000x reference)
//
#include <hip/hip_runtime.h>

// NaiveFourierKANLayer: y = cos-features @ W0^T + sin-features @ W1^T + bias
// N=32768, INPUTDIM=64, OUTDIM=256, GRIDSIZE=32 -> GEMM M=32768, N=256, K=4096
//
// R13 changes vs R12 (65.0 us, MfmaUtil 47.6, VALUBusy 32.6, conflicts 2.1M):
//  - MFMA 16x16x32 -> 32x32x16 (ceiling 2075 -> 2382 TF, half the issue
//    slots). R6 proved the 32x32 fragment + C/D maps correct; its failure
//    causes (VGPR spill at the 512-thr cap, degenerate XOR swizzle) are
//    removed here:
//  - No split-k: each wave owns a 64-col quarter x full K -> acc = 64 regs
//    (was 128), total ~170 << 256 cap; no red scratch, no reduction
//    epilogue -> direct stores via the R6-verified C/D map.
//  - A tile LDS is FRAGMENT-MAJOR: granule f*64+lane holds exactly what
//    lane reads for fragment f -> every ds_read_b128 is 64 contiguous
//    granules = minimum 8-cyc pattern, ZERO conflicts, no swizzle.
//    features() writes straight into fragment slots (kt-invariant addrs).
//  - B path re-indexed fragment-major for 32-col n-tiles x K=16 windows;
//    same rolling register reload (R9-verified pattern).
//  - Skeleton (BK=4 barrier amortization, ktquad, prologue/tail, bit-exact
//    feature chain, 2 blocks/CU) is R12-verbatim. LDS = 2x4x8KB = 64KB.

#define IDIM 64
#define ODIM 256
#define KDIM 4096
#define BM 64

typedef __attribute__((ext_vector_type(8))) unsigned short ushort8_t;
typedef __bf16 bf16x8 __attribute__((ext_vector_type(8)));
typedef float floatx16 __attribute__((ext_vector_type(16)));

__device__ __forceinline__ unsigned short f2bf_rne(float f) {
  unsigned int u = __float_as_uint(f);
  return (unsigned short)((u + 0x7FFFu + ((u >> 16) & 1u)) >> 16);
}

// ---- weight gather+convert: fc(2,256,64,32) fp32 -> Wr fragment-major bf16 ----
// 16B granule t: lane = t&63, bb = t>>6; bb = kt*32 + ntile*4 + ks
//   (ntile = 32-col tile 0..7, ks = 16-k window 0..3 within the kt)
// holds W[o][k] for o = ntile*32 + (lane&31),
//   chunk = 2*ks + (lane>>5)  ->  c = chunk>>2, g = (chunk&3)*8 + 1..8, i = kt
__global__ void __launch_bounds__(256) wconv(const float* __restrict__ fc,
                                             unsigned short* __restrict__ Wr) {
  int t = blockIdx.x * 256 + threadIdx.x;  // granule index 0..131071
  int lane = t & 63;
  int bb = t >> 6;
  int ks = bb & 3;
  int ntile = (bb >> 2) & 7;
  int kt = bb >> 5;
  int chunk = 2 * ks + (lane >> 5);
  int c = chunk >> 2;
  int g0 = (chunk & 3) * 8;
  int o = ntile * 32 + (lane & 31);
  const float* src = fc + ((size_t)c << 19) + o * 2048 + kt * 32 + g0;
  const float4 v0 = *(const float4*)(src);
  const float4 v1 = *(const float4*)(src + 4);
  ushort8_t r;
  r[0] = f2bf_rne(v0.x);
  r[1] = f2bf_rne(v0.y);
  r[2] = f2bf_rne(v0.z);
  r[3] = f2bf_rne(v0.w);
  r[4] = f2bf_rne(v1.x);
  r[5] = f2bf_rne(v1.y);
  r[6] = f2bf_rne(v1.z);
  r[7] = f2bf_rne(v1.w);
  *(ushort8_t*)(Wr + (size_t)t * 8) = r;
}

// ---- fused feature-gen + GEMM ----
__global__ void __launch_bounds__(256, 2) fkan_gemm(const float* __restrict__ X,
                                                    const unsigned short* __restrict__ Wr,
                                                    const float* __restrict__ bias,
                                                    float* __restrict__ out) {
  // A dbuf, fragment-major: [2 buf][4 kt][8 frag][64 lanes][8 ushorts] = 64KB
  __shared__ __align__(16) unsigned short As[2][4][4096];

  const int t = threadIdx.x;
  const int wv = t >> 6;    // wave 0..3 = n-quarter
  const int ln = t & 63;
  const int l31 = ln & 31;
  const int khi = ln >> 5;
  const int wn = wv;
  const int m0 = blockIdx.x * BM;

  // feature role: 4 threads per row, thread q owns g = 8q+1 .. 8q+8
  const int arow = t >> 2;  // 0..63
  const int q = t & 3;
  const float g0f = (float)(8 * q + 1);

  // fragment-major A write slots (kt-invariant, in ushorts):
  //   cos octave q -> chunk q   -> frag f = (arow>>5)*4 + (q>>1), lane (q&1)*32+(arow&31)
  //   sin octave q -> chunk 4+q -> frag f+2, same lane
  const int off_c = ((arow >> 5) * 4 + (q >> 1)) * 512 + ((q & 1) * 32 + (arow & 31)) * 8;
  const int off_s = off_c + 1024;  // +2 frags

  // B fragment-major base for this wave (blocks bb = kt*32 + wn*8 + nt*4 + ks)
  const unsigned short* const bwave = Wr + (size_t)(wn * 8) * 512 + ln * 8;

  floatx16 acc[2][2];
#pragma unroll
  for (int a = 0; a < 2; ++a)
#pragma unroll
    for (int b = 0; b < 2; ++b)
#pragma unroll
      for (int e = 0; e < 16; ++e) acc[a][b][e] = 0.0f;

  const float* xptr = X + (size_t)(m0 + arow) * IDIM;

  // ---- A staging: chain-of-8 Fourier recurrence -> two fragment granules
  auto features = [&](float xv, int buf, int j) {
    const float inv2pi = 0.15915494309189535f;
    float u = xv * inv2pi;  // x in revolutions
    float u0 = u * g0f;     // g0*x in revolutions
    float c1 = __builtin_amdgcn_cosf(u);
    float s1 = __builtin_amdgcn_sinf(u);
    float C = __builtin_amdgcn_cosf(u0);
    float S = __builtin_amdgcn_sinf(u0);
    bf16x8 cb, sb;
    cb[0] = (__bf16)C;
    sb[0] = (__bf16)S;
#pragma unroll
    for (int jj = 1; jj < 8; ++jj) {
      float Cn = __builtin_fmaf(C, c1, -(S * s1));
      float Sn = __builtin_fmaf(S, c1, (C * s1));
      C = Cn;
      S = Sn;
      cb[jj] = (__bf16)C;
      sb[jj] = (__bf16)S;
    }
    unsigned short* base = &As[buf][j][0];
    *(ushort8_t*)(base + off_c) = __builtin_bit_cast(ushort8_t, cb);
    *(ushort8_t*)(base + off_s) = __builtin_bit_cast(ushort8_t, sb);
  };

  bf16x8 breg[8];  // (nt*4+ks) B fragments, register-resident, rolling reload

  // ---- MFMA cluster for one kt: 8 linear b128 A-reads, 16 MFMAs (32x32x16)
  auto cluster = [&](int buf, int j, int reload_kt, bool do_reload) {
    const unsigned short* Abase = &As[buf][j][0];
    bf16x8 af[8];  // f = mt*4 + ks
#pragma unroll
    for (int f = 0; f < 8; ++f)
      af[f] = __builtin_bit_cast(bf16x8, *(const ushort8_t*)(Abase + f * 512 + ln * 8));
    const unsigned short* bn = bwave + (size_t)reload_kt * 16384;
    __builtin_amdgcn_s_setprio(1);
#pragma unroll
    for (int b = 0; b < 8; ++b) {
      const int nt = b >> 2;
      const int ks = b & 3;
      acc[0][nt] = __builtin_amdgcn_mfma_f32_32x32x16_bf16(
          af[ks], breg[b], acc[0][nt], 0, 0, 0);
      acc[1][nt] = __builtin_amdgcn_mfma_f32_32x32x16_bf16(
          af[4 + ks], breg[b], acc[1][nt], 0, 0, 0);
      // reload breg[b] right after its last use (WAR-safe in-order)
      if (do_reload)
        breg[b] = __builtin_bit_cast(bf16x8, *(const ushort8_t*)(bn + b * 512));
    }
    __builtin_amdgcn_s_setprio(0);
  };

  // ---- super-iteration: compute kt=4s..4s+3 from As[cur], prefetch
  //      features for kt=4s+4..4s+7 into As[nxt], ONE barrier.
  auto ktquad = [&](int s, int cur, int nxt) {
    int k0 = 4 * s;
    float xn0 = xptr[k0 + 4];
    float xn1 = xptr[k0 + 5];
    float xn2 = xptr[k0 + 6];
    float xn3 = xptr[k0 + 7];
    cluster(cur, 0, k0 + 1, true);
    features(xn0, nxt, 0);
    cluster(cur, 1, k0 + 2, true);
    features(xn1, nxt, 1);
    cluster(cur, 2, k0 + 3, true);
    features(xn2, nxt, 2);
    cluster(cur, 3, k0 + 4, true);
    features(xn3, nxt, 3);
    __syncthreads();
  };

  // ---- prologue: breg <- B(0); features kt 0..3 -> buf 0
#pragma unroll
  for (int b = 0; b < 8; ++b)
    breg[b] = __builtin_bit_cast(bf16x8, *(const ushort8_t*)(bwave + b * 512));
  features(xptr[0], 0, 0);
  features(xptr[1], 0, 1);
  features(xptr[2], 0, 2);
  features(xptr[3], 0, 3);
  __syncthreads();

  // ---- steady state: 15 super-iterations (s=0..14), unrolled x2
  for (int s = 0; s < 14; s += 2) {
    ktquad(s, 0, 1);
    ktquad(s + 1, 1, 0);
  }
  ktquad(14, 0, 1);  // computes kt 56..59, prefetches 60..63 -> buf 1

  // ---- tail: kt 60..63 from buf 1
  cluster(1, 0, 61, true);
  cluster(1, 1, 62, true);
  cluster(1, 2, 63, true);
  cluster(1, 3, 0, false);

  // ---- epilogue: direct store, 32x32 C/D map (verified R6):
  //      col = lane&31, row = (reg&3) + 8*(reg>>2) + 4*(lane>>5)
#pragma unroll
  for (int nt = 0; nt < 2; ++nt) {
    int col = wn * 64 + nt * 32 + l31;
    float bv = bias[col];
#pragma unroll
    for (int mt = 0; mt < 2; ++mt) {
      int rbase = m0 + mt * 32 + 4 * khi;
#pragma unroll
      for (int reg = 0; reg < 16; ++reg) {
        int row = rbase + (reg & 3) + 8 * (reg >> 2);
        out[(size_t)row * ODIM + col] = acc[mt][nt][reg] + bv;
      }
    }
  }
}

extern "C" void kernel_launch(void* const* d_in, const int* in_sizes, int n_in,
                              void* d_out, int out_size, void* d_ws, size_t ws_size,
                              hipStream_t stream) {
  const float* x = (const float*)d_in[0];
  const float* fc = (const float*)d_in[1];
  const float* bias = (const float*)d_in[2];
  float* out = (float*)d_out;
  unsigned short* Wr = (unsigned short*)d_ws;  // 2 MB of workspace

  hipLaunchKernelGGL(wconv, dim3(512), dim3(256), 0, stream, fc, Wr);
  hipLaunchKernelGGL(fkan_gemm, dim3(512), dim3(256), 0, stream, x, Wr, bias, out);
}